// Round 4
// baseline (124.873 us; speedup 1.0000x reference)
//
#include <hip/hip_runtime.h>

// QuantumDMRGLayer: B=2048, L=196, M=16, NBL=10, pos_label=98 (fixed by setup).
// Round-11: r1-r3 proved occupancy can't beat the ~1000cyc/site serial chain
// (multi-wave overlap saturates at ~2.4x) and basis decomposition inflates
// work 16x. v11 keeps r0's best-measured structure (128 waves x 32 samples,
// verified epilogue) and attacks the SERIAL PATH instead:
//   1) PAIR-SITE steps: prep computes, per site pair, the 4 combo products
//      Q_ab = A_a,p * A_b,p+1 in fp32. One chain step = 2 sites: 2 MFMA-sets
//      (4 matrices), 4 coefficients x_a,p*x_b,p+1. Same MFMA count per site,
//      HALF the serial steps (98->49, 96->48).
//   2) UNCHAINED split-bf16: D = Ghi*Vhi + Ghi*Vlo + Glo*Vhi computed in 3
//      INDEPENDENT zero-init accumulators (summed in the VALU combine), so
//      the per-step MFMA critical path is 1 latency, not 3.
// G layout per MFMA-set, pi row-permutation, split-bf16 scheme, init, and
// out_kernel are verbatim from the verified r0 kernel.

typedef __attribute__((ext_vector_type(8))) short short8;
typedef __attribute__((ext_vector_type(16))) float floatx16;

#define PSET_DW 512                    // dwords per MFMA-set (hi 256 | lo 256)
#define PAIR_DW (2 * PSET_DW)          // 2 sets per pair-step
#define LSTEPS 49                      // left: 98 sites = 49 pairs
#define RSTEPS 48                      // right: 96 sites = 48 pairs
#define RBASE_DW (LSTEPS * PAIR_DW)    // right stream base
#define WST_OFF_DW ((LSTEPS + RSTEPS) * PAIR_DW)   // states after streams
// WS: pair streams 97*4KB = 388KB, then WST [dir][2048][16] floats (256KB)

__device__ __forceinline__ unsigned bf16_rne(unsigned u) {
    return (u + 0x7FFFu + ((u >> 16) & 1u)) >> 16;
}

// ---- prep: per site-pair, 4 fp32 combo products -> split-bf16 G sets ----
// Stream step t, set s_ (0,1), A-row r (0..31): d=r>>4, sig=pi(r&15),
// combo i = 2*s_+d = (b0=s_, b1=d), value:
//   left  (transposed store): G[r,k] = Q_i[k, sig]
//   right (direct store):     G[r,k] = Q_i[sig, k]
// where Q_i = A_{b0,a0} * A_{b1,a1} (fp32), a0/a1 = the pair's AM rows.
// Left step t: a0=2t, a1=2t+1. Right step t: a0=192-2t, a1=193-2t
// (right chain processes pairs from the right end inward).
__global__ __launch_bounds__(256)
void prep_pair(const float* __restrict__ AM, unsigned* __restrict__ WS)
{
    __shared__ float sA0[2][16][16];
    __shared__ float sA1[2][16][16];
    const int pidx = blockIdx.x;               // 0..96
    const int tid  = threadIdx.x;
    const int dir  = (pidx >= LSTEPS) ? 1 : 0;
    const int t    = dir ? (pidx - LSTEPS) : pidx;
    const int a0   = dir ? (192 - 2 * t) : (2 * t);
    const int a1   = a0 + 1;

    for (int i = tid; i < 512; i += 256) {
        ((float*)sA0)[i] = AM[a0 * 512 + i];
        ((float*)sA1)[i] = AM[a1 * 512 + i];
    }
    __syncthreads();

    unsigned* gp = WS + (dir ? (RBASE_DW + t * PAIR_DW) : (t * PAIR_DW));
    for (int u = tid; u < 512; u += 256) {     // 2 sets x 64 lanes x 4 dwords
        const int s_   = u >> 8;
        const int lane = (u & 255) >> 2;
        const int w_   = u & 3;
        const int r    = lane & 31;
        const int kb   = (lane >> 5) << 3;
        const int d    = r >> 4;
        const int rl   = r & 15;
        const int sig  = (rl & 3) | ((rl & 4) << 1) | ((rl & 8) >> 1);  // pi
        const int b0 = s_, b1 = d;
        const int k0 = kb + 2 * w_;
        float q0 = 0.f, q1 = 0.f;
        if (dir == 0) {
#pragma unroll
            for (int m_ = 0; m_ < 16; ++m_) {
                const float a1v = sA1[b1][m_][sig];
                q0 = fmaf(sA0[b0][k0][m_],     a1v, q0);
                q1 = fmaf(sA0[b0][k0 + 1][m_], a1v, q1);
            }
        } else {
#pragma unroll
            for (int m_ = 0; m_ < 16; ++m_) {
                const float a0v = sA0[b0][sig][m_];
                q0 = fmaf(a0v, sA1[b1][m_][k0],     q0);
                q1 = fmaf(a0v, sA1[b1][m_][k0 + 1], q1);
            }
        }
        const unsigned u0 = __float_as_uint(q0), u1 = __float_as_uint(q1);
        const unsigned h0 = bf16_rne(u0), h1 = bf16_rne(u1);
        const float l0f = q0 - __uint_as_float(h0 << 16);
        const float l1f = q1 - __uint_as_float(h1 << 16);
        const unsigned lo0 = bf16_rne(__float_as_uint(l0f));
        const unsigned lo1 = bf16_rne(__float_as_uint(l1f));
        gp[s_ * PSET_DW + lane * 4 + w_]       = (h1 << 16) | h0;
        gp[s_ * PSET_DW + 256 + lane * 4 + w_] = (lo1 << 16) | lo0;
    }
}

// ---- main chain: 1 wave = 32 samples x 1 direction, pair steps ----
__global__ __launch_bounds__(64, 1)
void chain_kernel(const float* __restrict__ X,
                  const float* __restrict__ AL,
                  const float* __restrict__ AR,
                  const unsigned* __restrict__ WS,
                  float* __restrict__ WST)
{
    const int lane = threadIdx.x;              // 0..63
    const int dir  = blockIdx.x & 1;
    const int s    = (blockIdx.x >> 1) * 32 + (lane & 31);
    const int kb   = (lane >> 5) << 3;         // this lane's k-half base
    const float* Xs = X + s * 392;
    const unsigned* Gb = WS + (dir ? RBASE_DW : 0) + lane * 4;
    const int nsteps = dir ? RSTEPS : LSTEPS;

    // split fp32 comps -> packed bf16 hi/lo fragments (r0-verified pack)
    float w[8];
    int4 vh4, vl4;
    auto pack = [&]() {
#pragma unroll
        for (int q = 0; q < 4; ++q) {
            const unsigned u0 = __float_as_uint(w[2 * q]);
            const unsigned u1 = __float_as_uint(w[2 * q + 1]);
            const unsigned h0 = u0 & 0xFFFF0000u, h1 = u1 & 0xFFFF0000u;
            const float l0 = w[2 * q]     - __uint_as_float(h0);
            const float l1 = w[2 * q + 1] - __uint_as_float(h1);
            ((unsigned*)&vh4)[q] = h1 | (h0 >> 16);
            ((unsigned*)&vl4)[q] = (__float_as_uint(l1) & 0xFFFF0000u) |
                                   (__float_as_uint(l0) >> 16);
        }
    };

    // ---- init bond vector (verbatim r0) ----
    const float* Ai = dir ? AR : AL;
    const float2 xi = *(const float2*)(Xs + (dir ? 390 : 0));
#pragma unroll
    for (int j = 0; j < 8; ++j)
        w[j] = xi.x * Ai[kb + j] + xi.y * Ai[16 + kb + j];
    pack();

    // ---- 2-step register ring ----
    int4 GH[2][2], GL[2][2];
    float2 xp[2], xq[2];
    auto ldstep = [&](int t, int slot) {
        const unsigned* gp = Gb + t * PAIR_DW;
        GH[slot][0] = *(const int4*)(gp);
        GL[slot][0] = *(const int4*)(gp + 256);
        GH[slot][1] = *(const int4*)(gp + PSET_DW);
        GL[slot][1] = *(const int4*)(gp + PSET_DW + 256);
        const int xo = dir ? (386 - 4 * t) : (4 * t + 2);
        xp[slot] = *(const float2*)(Xs + xo);
        xq[slot] = *(const float2*)(Xs + xo + 2);
    };
    ldstep(0, 0);
    ldstep(1, 1);

    for (int t = 0; t < nsteps; ++t) {
        const int slot = t & 1;
        const short8 ah0 = *(const short8*)&GH[slot][0];
        const short8 al0 = *(const short8*)&GL[slot][0];
        const short8 ah1 = *(const short8*)&GH[slot][1];
        const short8 al1 = *(const short8*)&GL[slot][1];
        const float2 xpc = xp[slot], xqc = xq[slot];
        if (t + 2 < nsteps) ldstep(t + 2, slot);   // operands copied above

        const short8 bh = *(const short8*)&vh4;
        const short8 bl = *(const short8*)&vl4;
        // 6 INDEPENDENT MFMAs (no C chaining): critical path = 1 latency
        floatx16 Dhh0 = {}, Dhl0 = {}, Dlh0 = {};
        floatx16 Dhh1 = {}, Dhl1 = {}, Dlh1 = {};
        Dhh0 = __builtin_amdgcn_mfma_f32_32x32x16_bf16(ah0, bh, Dhh0, 0, 0, 0);
        Dhh1 = __builtin_amdgcn_mfma_f32_32x32x16_bf16(ah1, bh, Dhh1, 0, 0, 0);
        Dhl0 = __builtin_amdgcn_mfma_f32_32x32x16_bf16(ah0, bl, Dhl0, 0, 0, 0);
        Dhl1 = __builtin_amdgcn_mfma_f32_32x32x16_bf16(ah1, bl, Dhl1, 0, 0, 0);
        Dlh0 = __builtin_amdgcn_mfma_f32_32x32x16_bf16(al0, bh, Dlh0, 0, 0, 0);
        Dlh1 = __builtin_amdgcn_mfma_f32_32x32x16_bf16(al1, bh, Dlh1, 0, 0, 0);

        // coefficients: c_{b0*2+b1} = x_{b0}(first site) * x_{b1}(second)
        const float c0 = xpc.x * xqc.x, c1 = xpc.x * xqc.y;
        const float c2 = xpc.y * xqc.x, c3 = xpc.y * xqc.y;
#pragma unroll
        for (int j = 0; j < 8; ++j) {
            const float e0  = (Dhh0[j]     + Dhl0[j])     + Dlh0[j];
            const float e0h = (Dhh0[j + 8] + Dhl0[j + 8]) + Dlh0[j + 8];
            const float e1  = (Dhh1[j]     + Dhl1[j])     + Dlh1[j];
            const float e1h = (Dhh1[j + 8] + Dhl1[j + 8]) + Dlh1[j + 8];
            w[j] = fmaf(c0, e0, fmaf(c1, e0h, fmaf(c2, e1, c3 * e1h)));
        }
        pack();
    }

    // ---- final state (fp32): comps kb..kb+7 of sample s (verbatim r0) ----
    float* st = WST + (dir * 2048 + s) * 16 + kb;
    *(float4*)(st)     = make_float4(w[0], w[1], w[2], w[3]);
    *(float4*)(st + 4) = make_float4(w[4], w[5], w[6], w[7]);
}

// ---- epilogue: out[s,l] = sum_{m,n} L[m,s] T[m,n,l] R[n,s] (verbatim r0) ----
__global__ __launch_bounds__(256)
void out_kernel(const float* __restrict__ T, const float* __restrict__ WST,
                float* __restrict__ OUT)
{
    __shared__ float sT[2560];
    const int tid = threadIdx.x;
    for (int k = tid; k < 640; k += 256)
        ((float4*)sT)[k] = ((const float4*)T)[k];
    __syncthreads();
    const int t = blockIdx.x * 256 + tid;      // < 20480
    const int s = t / 10, l = t - s * 10;
    const float* L = WST + s * 16;
    const float* R = WST + 2048 * 16 + s * 16;
    const float4 Ra = *(const float4*)(R);
    const float4 Rb = *(const float4*)(R + 4);
    const float4 Rc = *(const float4*)(R + 8);
    const float4 Rd = *(const float4*)(R + 12);
    float acc = 0.f;
#pragma unroll
    for (int m = 0; m < 16; ++m) {
        const float lm = L[m];
        const float* Tp = sT + m * 160 + l;
        acc = fmaf(lm * Ra.x, Tp[0],   acc);
        acc = fmaf(lm * Ra.y, Tp[10],  acc);
        acc = fmaf(lm * Ra.z, Tp[20],  acc);
        acc = fmaf(lm * Ra.w, Tp[30],  acc);
        acc = fmaf(lm * Rb.x, Tp[40],  acc);
        acc = fmaf(lm * Rb.y, Tp[50],  acc);
        acc = fmaf(lm * Rb.z, Tp[60],  acc);
        acc = fmaf(lm * Rb.w, Tp[70],  acc);
        acc = fmaf(lm * Rc.x, Tp[80],  acc);
        acc = fmaf(lm * Rc.y, Tp[90],  acc);
        acc = fmaf(lm * Rc.z, Tp[100], acc);
        acc = fmaf(lm * Rc.w, Tp[110], acc);
        acc = fmaf(lm * Rd.x, Tp[120], acc);
        acc = fmaf(lm * Rd.y, Tp[130], acc);
        acc = fmaf(lm * Rd.z, Tp[140], acc);
        acc = fmaf(lm * Rd.w, Tp[150], acc);
    }
    OUT[t] = acc;
}

extern "C" void kernel_launch(void* const* d_in, const int* in_sizes, int n_in,
                              void* d_out, int out_size, void* d_ws, size_t ws_size,
                              hipStream_t stream)
{
    const float* X  = (const float*)d_in[0];   // (2048,196,2)
    const float* AL = (const float*)d_in[1];   // (2,16)
    const float* AM = (const float*)d_in[2];   // (194,2,16,16)
    const float* AR = (const float*)d_in[3];   // (2,16)
    const float* T  = (const float*)d_in[4];   // (16,16,10)
    (void)in_sizes; (void)n_in; (void)out_size; (void)ws_size;
    unsigned* WS = (unsigned*)d_ws;            // pair streams: 388 KB
    float* WST   = (float*)d_ws + WST_OFF_DW;  // states: 256 KB
    float* OUT   = (float*)d_out;              // (2048,10)

    hipLaunchKernelGGL(prep_pair,    dim3(97),  dim3(256), 0, stream, AM, WS);
    hipLaunchKernelGGL(chain_kernel, dim3(128), dim3(64),  0, stream,
                       X, AL, AR, WS, WST);
    hipLaunchKernelGGL(out_kernel,   dim3(80),  dim3(256), 0, stream,
                       T, WST, OUT);
}

// Round 5
// 85.426 us; speedup vs baseline: 1.4618x; 1.4618x over previous
//
#include <hip/hip_runtime.h>

// QuantumDMRGLayer: B=2048, L=196, M=16, NBL=10, pos_label=98 (fixed by setup).
// Round-12: r4's pair-step chain was right but crippled by two bugs the
// counters exposed (VGPR=68 + LDS_Block=5120 + 483k bank conflicts on a
// no-LDS kernel): (a) runtime-indexed ring slot -> arrays demoted to LDS/
// scratch, (b) 6 independent zero-init accumulators -> 192 accvgpr-traffic
// ops/step. v12 fixes both, keeping the verified prep_pair/out_kernel:
//   - unroll-2 main loop: ring slot is a compile-time constant -> all ring
//     state in registers.
//   - 2 CHAINED accumulators (one 3-MFMA chain per set; chains independent,
//     interleaved issue) with a persistent zero C hoisted out of the loop ->
//     per-step critical path = 3 MFMA deps (same as r0's per-site) but HALF
//     the steps (49 vs 98).
// Per-pair math (Q_ab combos, coeffs c_i = x_b0(p)*x_b1(p+1)) verified by r4.

typedef __attribute__((ext_vector_type(8))) short short8;
typedef __attribute__((ext_vector_type(16))) float floatx16;

#define PSET_DW 512                    // dwords per MFMA-set (hi 256 | lo 256)
#define PAIR_DW (2 * PSET_DW)          // 2 sets per pair-step
#define LSTEPS 49                      // left: 98 sites = 49 pairs
#define RSTEPS 48                      // right: 96 sites = 48 pairs
#define RBASE_DW (LSTEPS * PAIR_DW)    // right stream base
#define WST_OFF_DW ((LSTEPS + RSTEPS) * PAIR_DW)   // states after streams
// WS: pair streams 97*4KB = 388KB, then WST [dir][2048][16] floats (256KB)

__device__ __forceinline__ unsigned bf16_rne(unsigned u) {
    return (u + 0x7FFFu + ((u >> 16) & 1u)) >> 16;
}

// ---- prep: per site-pair, 4 fp32 combo products -> split-bf16 G sets ----
// (verbatim from r4, harness-verified)
__global__ __launch_bounds__(256)
void prep_pair(const float* __restrict__ AM, unsigned* __restrict__ WS)
{
    __shared__ float sA0[2][16][16];
    __shared__ float sA1[2][16][16];
    const int pidx = blockIdx.x;               // 0..96
    const int tid  = threadIdx.x;
    const int dir  = (pidx >= LSTEPS) ? 1 : 0;
    const int t    = dir ? (pidx - LSTEPS) : pidx;
    const int a0   = dir ? (192 - 2 * t) : (2 * t);
    const int a1   = a0 + 1;

    for (int i = tid; i < 512; i += 256) {
        ((float*)sA0)[i] = AM[a0 * 512 + i];
        ((float*)sA1)[i] = AM[a1 * 512 + i];
    }
    __syncthreads();

    unsigned* gp = WS + (dir ? (RBASE_DW + t * PAIR_DW) : (t * PAIR_DW));
    for (int u = tid; u < 512; u += 256) {     // 2 sets x 64 lanes x 4 dwords
        const int s_   = u >> 8;
        const int lane = (u & 255) >> 2;
        const int w_   = u & 3;
        const int r    = lane & 31;
        const int kb   = (lane >> 5) << 3;
        const int d    = r >> 4;
        const int rl   = r & 15;
        const int sig  = (rl & 3) | ((rl & 4) << 1) | ((rl & 8) >> 1);  // pi
        const int b0 = s_, b1 = d;
        const int k0 = kb + 2 * w_;
        float q0 = 0.f, q1 = 0.f;
        if (dir == 0) {
#pragma unroll
            for (int m_ = 0; m_ < 16; ++m_) {
                const float a1v = sA1[b1][m_][sig];
                q0 = fmaf(sA0[b0][k0][m_],     a1v, q0);
                q1 = fmaf(sA0[b0][k0 + 1][m_], a1v, q1);
            }
        } else {
#pragma unroll
            for (int m_ = 0; m_ < 16; ++m_) {
                const float a0v = sA0[b0][sig][m_];
                q0 = fmaf(a0v, sA1[b1][m_][k0],     q0);
                q1 = fmaf(a0v, sA1[b1][m_][k0 + 1], q1);
            }
        }
        const unsigned u0 = __float_as_uint(q0), u1 = __float_as_uint(q1);
        const unsigned h0 = bf16_rne(u0), h1 = bf16_rne(u1);
        const float l0f = q0 - __uint_as_float(h0 << 16);
        const float l1f = q1 - __uint_as_float(h1 << 16);
        const unsigned lo0 = bf16_rne(__float_as_uint(l0f));
        const unsigned lo1 = bf16_rne(__float_as_uint(l1f));
        gp[s_ * PSET_DW + lane * 4 + w_]       = (h1 << 16) | h0;
        gp[s_ * PSET_DW + 256 + lane * 4 + w_] = (lo1 << 16) | lo0;
    }
}

// ---- main chain: 1 wave = 32 samples x 1 direction, pair steps ----
__global__ __launch_bounds__(64, 1)
void chain_kernel(const float* __restrict__ X,
                  const float* __restrict__ AL,
                  const float* __restrict__ AR,
                  const unsigned* __restrict__ WS,
                  float* __restrict__ WST)
{
    const int lane = threadIdx.x;              // 0..63
    const int dir  = blockIdx.x & 1;
    const int s    = (blockIdx.x >> 1) * 32 + (lane & 31);
    const int kb   = (lane >> 5) << 3;         // this lane's k-half base
    const float* Xs = X + s * 392;
    const unsigned* Gb = WS + (dir ? RBASE_DW : 0) + lane * 4;
    const int nsteps = dir ? RSTEPS : LSTEPS;

    // split fp32 comps -> packed bf16 hi/lo fragments (r0-verified pack)
    float w[8];
    int4 vh4, vl4;
    auto pack = [&]() {
#pragma unroll
        for (int q = 0; q < 4; ++q) {
            const unsigned u0 = __float_as_uint(w[2 * q]);
            const unsigned u1 = __float_as_uint(w[2 * q + 1]);
            const unsigned h0 = u0 & 0xFFFF0000u, h1 = u1 & 0xFFFF0000u;
            const float l0 = w[2 * q]     - __uint_as_float(h0);
            const float l1 = w[2 * q + 1] - __uint_as_float(h1);
            ((unsigned*)&vh4)[q] = h1 | (h0 >> 16);
            ((unsigned*)&vl4)[q] = (__float_as_uint(l1) & 0xFFFF0000u) |
                                   (__float_as_uint(l0) >> 16);
        }
    };

    // ---- init bond vector (verbatim r0) ----
    const float* Ai = dir ? AR : AL;
    const float2 xi = *(const float2*)(Xs + (dir ? 390 : 0));
#pragma unroll
    for (int j = 0; j < 8; ++j)
        w[j] = xi.x * Ai[kb + j] + xi.y * Ai[16 + kb + j];
    pack();

    const floatx16 Z = {};                     // persistent zero C (hoisted)

    // ---- 2-slot register ring, STATIC indexing via unroll-2 ----
    int4 GH0[2], GL0[2], GH1[2], GL1[2];       // [slot] x set0/set1
    float2 xp[2], xq[2];
    {
        const unsigned* gp0 = Gb;
        GH0[0] = *(const int4*)(gp0);
        GL0[0] = *(const int4*)(gp0 + 256);
        GH1[0] = *(const int4*)(gp0 + PSET_DW);
        GL1[0] = *(const int4*)(gp0 + PSET_DW + 256);
        const int xo0 = dir ? 386 : 2;
        xp[0] = *(const float2*)(Xs + xo0);
        xq[0] = *(const float2*)(Xs + xo0 + 2);
        const unsigned* gp1 = Gb + PAIR_DW;
        GH0[1] = *(const int4*)(gp1);
        GL0[1] = *(const int4*)(gp1 + 256);
        GH1[1] = *(const int4*)(gp1 + PSET_DW);
        GL1[1] = *(const int4*)(gp1 + PSET_DW + 256);
        const int xo1 = dir ? 382 : 6;
        xp[1] = *(const float2*)(Xs + xo1);
        xq[1] = *(const float2*)(Xs + xo1 + 2);
    }

    for (int c = 0; c < 25; ++c) {
#pragma unroll
        for (int half = 0; half < 2; ++half) { // slot = half: compile-time
            const int t = 2 * c + half;
            if (t < nsteps) {
                const short8 ah0 = *(const short8*)&GH0[half];
                const short8 al0 = *(const short8*)&GL0[half];
                const short8 ah1 = *(const short8*)&GH1[half];
                const short8 al1 = *(const short8*)&GL1[half];
                const float2 xpc = xp[half], xqc = xq[half];

                // prefetch step t+2 into this slot (operands copied above)
                const int tn = (t + 2 < nsteps) ? (t + 2) : t;
                const unsigned* gp = Gb + tn * PAIR_DW;
                GH0[half] = *(const int4*)(gp);
                GL0[half] = *(const int4*)(gp + 256);
                GH1[half] = *(const int4*)(gp + PSET_DW);
                GL1[half] = *(const int4*)(gp + PSET_DW + 256);
                const int xo = dir ? (386 - 4 * tn) : (4 * tn + 2);
                xp[half] = *(const float2*)(Xs + xo);
                xq[half] = *(const float2*)(Xs + xo + 2);

                const short8 bh = *(const short8*)&vh4;
                const short8 bl = *(const short8*)&vl4;
                // two independent 3-MFMA chains, interleaved issue
                floatx16 D0, D1;
                D0 = __builtin_amdgcn_mfma_f32_32x32x16_bf16(ah0, bh, Z,  0, 0, 0);
                D1 = __builtin_amdgcn_mfma_f32_32x32x16_bf16(ah1, bh, Z,  0, 0, 0);
                D0 = __builtin_amdgcn_mfma_f32_32x32x16_bf16(ah0, bl, D0, 0, 0, 0);
                D1 = __builtin_amdgcn_mfma_f32_32x32x16_bf16(ah1, bl, D1, 0, 0, 0);
                D0 = __builtin_amdgcn_mfma_f32_32x32x16_bf16(al0, bh, D0, 0, 0, 0);
                D1 = __builtin_amdgcn_mfma_f32_32x32x16_bf16(al1, bh, D1, 0, 0, 0);

                // c_{2*b0+b1} = x_{b0}(first site) * x_{b1}(second site)
                const float c0 = xpc.x * xqc.x, c1 = xpc.x * xqc.y;
                const float c2 = xpc.y * xqc.x, c3 = xpc.y * xqc.y;
#pragma unroll
                for (int j = 0; j < 8; ++j)
                    w[j] = fmaf(c0, D0[j],
                           fmaf(c1, D0[j + 8],
                           fmaf(c2, D1[j], c3 * D1[j + 8])));
                pack();
            }
        }
    }

    // ---- final state (fp32): comps kb..kb+7 of sample s (verbatim r0) ----
    float* st = WST + (dir * 2048 + s) * 16 + kb;
    *(float4*)(st)     = make_float4(w[0], w[1], w[2], w[3]);
    *(float4*)(st + 4) = make_float4(w[4], w[5], w[6], w[7]);
}

// ---- epilogue: out[s,l] = sum_{m,n} L[m,s] T[m,n,l] R[n,s] (verbatim r0) ----
__global__ __launch_bounds__(256)
void out_kernel(const float* __restrict__ T, const float* __restrict__ WST,
                float* __restrict__ OUT)
{
    __shared__ float sT[2560];
    const int tid = threadIdx.x;
    for (int k = tid; k < 640; k += 256)
        ((float4*)sT)[k] = ((const float4*)T)[k];
    __syncthreads();
    const int t = blockIdx.x * 256 + tid;      // < 20480
    const int s = t / 10, l = t - s * 10;
    const float* L = WST + s * 16;
    const float* R = WST + 2048 * 16 + s * 16;
    const float4 Ra = *(const float4*)(R);
    const float4 Rb = *(const float4*)(R + 4);
    const float4 Rc = *(const float4*)(R + 8);
    const float4 Rd = *(const float4*)(R + 12);
    float acc = 0.f;
#pragma unroll
    for (int m = 0; m < 16; ++m) {
        const float lm = L[m];
        const float* Tp = sT + m * 160 + l;
        acc = fmaf(lm * Ra.x, Tp[0],   acc);
        acc = fmaf(lm * Ra.y, Tp[10],  acc);
        acc = fmaf(lm * Ra.z, Tp[20],  acc);
        acc = fmaf(lm * Ra.w, Tp[30],  acc);
        acc = fmaf(lm * Rb.x, Tp[40],  acc);
        acc = fmaf(lm * Rb.y, Tp[50],  acc);
        acc = fmaf(lm * Rb.z, Tp[60],  acc);
        acc = fmaf(lm * Rb.w, Tp[70],  acc);
        acc = fmaf(lm * Rc.x, Tp[80],  acc);
        acc = fmaf(lm * Rc.y, Tp[90],  acc);
        acc = fmaf(lm * Rc.z, Tp[100], acc);
        acc = fmaf(lm * Rc.w, Tp[110], acc);
        acc = fmaf(lm * Rd.x, Tp[120], acc);
        acc = fmaf(lm * Rd.y, Tp[130], acc);
        acc = fmaf(lm * Rd.z, Tp[140], acc);
        acc = fmaf(lm * Rd.w, Tp[150], acc);
    }
    OUT[t] = acc;
}

extern "C" void kernel_launch(void* const* d_in, const int* in_sizes, int n_in,
                              void* d_out, int out_size, void* d_ws, size_t ws_size,
                              hipStream_t stream)
{
    const float* X  = (const float*)d_in[0];   // (2048,196,2)
    const float* AL = (const float*)d_in[1];   // (2,16)
    const float* AM = (const float*)d_in[2];   // (194,2,16,16)
    const float* AR = (const float*)d_in[3];   // (2,16)
    const float* T  = (const float*)d_in[4];   // (16,16,10)
    (void)in_sizes; (void)n_in; (void)out_size; (void)ws_size;
    unsigned* WS = (unsigned*)d_ws;            // pair streams: 388 KB
    float* WST   = (float*)d_ws + WST_OFF_DW;  // states: 256 KB
    float* OUT   = (float*)d_out;              // (2048,10)

    hipLaunchKernelGGL(prep_pair,    dim3(97),  dim3(256), 0, stream, AM, WS);
    hipLaunchKernelGGL(chain_kernel, dim3(128), dim3(64),  0, stream,
                       X, AL, AR, WS, WST);
    hipLaunchKernelGGL(out_kernel,   dim3(80),  dim3(256), 0, stream,
                       T, WST, OUT);
}